// Round 12
// baseline (547.132 us; speedup 1.0000x reference)
//
#include <hip/hip_runtime.h>
#include <hip/hip_bf16.h>

#define V_IN 128
#define U_IN 64
#define HID 128
#define K1  (V_IN + HID + U_IN)   // 320

typedef __attribute__((ext_vector_type(8))) short bf16x8;
typedef __attribute__((ext_vector_type(4))) float f32x4;

static __device__ __forceinline__ unsigned short f2bf(float f) {
    __hip_bfloat16 h = __float2bfloat16(f);
    union { __hip_bfloat16 h; unsigned short u; } v; v.h = h;
    return v.u;
}
static __device__ __forceinline__ unsigned int f2bf2(float lo, float hi) {
    __hip_bfloat162 h2 = __float22bfloat162_rn(make_float2(lo, hi));  // v_cvt_pk_bf16_f32
    union { __hip_bfloat162 h; unsigned int u; } v; v.h = h2;
    return v.u;
}

// ---------- fused: zero deg + W1/W2 -> bf16 transposed ----------
__global__ __launch_bounds__(256) void zero_prep(
    const float* __restrict__ W1, const float* __restrict__ W2,
    unsigned short* __restrict__ Wt1, unsigned short* __restrict__ Wt2,
    int* __restrict__ deg, int N)
{
    int id = blockIdx.x * 256 + threadIdx.x;
    if (id < N) deg[id] = 0;
    if (id < HID * K1) {                     // Wt1: [128][320]
        int c = id / K1, k = id - c * K1;
        Wt1[id] = f2bf(W1[(size_t)k * HID + c]);
    }
    if (id < HID * HID) {                    // Wt2: [128][128]
        int c = id >> 7, k = id & 127;
        Wt2[id] = f2bf(W2[(size_t)k * HID + c]);
    }
}

// ---------- CSR build ----------

__global__ __launch_bounds__(256) void hist_kernel(
    const int* __restrict__ col, int* __restrict__ deg, int E)
{
    int e = blockIdx.x * 256 + threadIdx.x;
    if (e < E) atomicAdd(&deg[col[e]], 1);
}

__global__ __launch_bounds__(256) void scan_partial(
    const int* __restrict__ deg, int* __restrict__ blockSums, int N)
{
    __shared__ int sdata[256];
    int base = blockIdx.x * 1024;
    int tid  = threadIdx.x;
    int s = 0;
    #pragma unroll
    for (int j = 0; j < 4; ++j) {
        int i = base + tid * 4 + j;
        if (i < N) s += deg[i];
    }
    sdata[tid] = s;
    __syncthreads();
    for (int off = 128; off > 0; off >>= 1) {
        if (tid < off) sdata[tid] += sdata[tid + off];
        __syncthreads();
    }
    if (tid == 0) blockSums[blockIdx.x] = sdata[0];
}

// final: computes its own blockSums prefix (separate scan kernel folded in)
__global__ __launch_bounds__(256) void scan_final(
    const int* __restrict__ deg, const int* __restrict__ blockSums,
    int* __restrict__ offsets, int* __restrict__ cur, int N, int E)
{
    __shared__ int sdata[256];
    __shared__ int rdata[256];
    int tid = threadIdx.x;

    int part = 0;
    for (int i = tid; i < (int)blockIdx.x; i += 256) part += blockSums[i];
    rdata[tid] = part;
    __syncthreads();
    for (int off = 128; off > 0; off >>= 1) {
        if (tid < off) rdata[tid] += rdata[tid + off];
        __syncthreads();
    }
    const int blockPrefix = rdata[0];

    int base = blockIdx.x * 1024;
    int loc[4];
    int s = 0;
    #pragma unroll
    for (int j = 0; j < 4; ++j) {
        int i = base + tid * 4 + j;
        loc[j] = (i < N) ? deg[i] : 0;
        s += loc[j];
    }
    int mine = s;
    sdata[tid] = s;
    __syncthreads();
    for (int off = 1; off < 256; off <<= 1) {
        int t = (tid >= off) ? sdata[tid - off] : 0;
        __syncthreads();
        sdata[tid] += t;
        __syncthreads();
    }
    int prefix = blockPrefix + sdata[tid] - mine;
    #pragma unroll
    for (int j = 0; j < 4; ++j) {
        int i = base + tid * 4 + j;
        if (i < N) { offsets[i] = prefix; cur[i] = prefix; prefix += loc[j]; }
    }
    if (blockIdx.x == 0 && tid == 0) offsets[N] = E;
}

__global__ __launch_bounds__(256) void fill_kernel(
    const int* __restrict__ col, int* __restrict__ cur,
    int* __restrict__ eidx, int E)
{
    int e = blockIdx.x * 256 + threadIdx.x;
    if (e < E) {
        int p = atomicAdd(&cur[col[e]], 1);
        eidx[p] = e;
    }
}

// ---------- fused gather + 2-layer MLP via bf16 MFMA ----------
// block = 512 threads = 8 waves; wave w owns output cols [16w, 16w+15];
// ROWS = 32 nodes/block, two 16-row tiles per wave share its in-reg W frags.
// R12 gather: EDGE-PARALLEL, perfectly balanced. Tile edges staged packed
// (e<<5|row); task space = cnt*32 chunks strided over all threads; fp32
// accumulation in LDS via ds_add_f32. Lane c handles words {c, c+32, c+64,
// c+96} of an edge row: loads are 128B-coalesced per instr, ds_adds are
// stride-1 across lanes -> 2 lanes/bank = conflict-free (m136).
#define ROWS 32
#define LDA_E 328
#define LDH_E 136
#define ECAP 1280

__global__ __launch_bounds__(512, 4) void mlp_mfma(
    const float* __restrict__ x,
    const float* __restrict__ edge_attr,
    const int*   __restrict__ offsets,
    const int*   __restrict__ eidx,
    const float* __restrict__ u,
    const int*   __restrict__ batch,
    const unsigned short* __restrict__ Wt1,
    const unsigned short* __restrict__ Wt2,
    const float* __restrict__ b1, const float* __restrict__ b2,
    float* __restrict__ out, int N)
{
    __shared__ __align__(16) unsigned short A[ROWS * LDA_E];
    __shared__ __align__(16) unsigned short H[ROWS * LDH_E];
    __shared__ float Af[ROWS * HID];     // 16 KB fp32 agg accumulators
    __shared__ int  Eidx[ECAP];          // packed (e << 5) | row
    __shared__ int  Soff[ROWS + 1];
    const int tid  = threadIdx.x;
    const int n0   = blockIdx.x * ROWS;
    const int lane = tid & 63;
    const int wave = tid >> 6;       // 0..7 = which 16-col slice
    const int l15  = lane & 15;
    const int lhi  = lane >> 4;      // 0..3
    const int wcol = wave * 16 + l15;

    // ---- phase 0: Soff slice, zero Af, stage x/u
    const int nEnd = (n0 + ROWS < N) ? n0 + ROWS : N;
    if (tid <= ROWS) {
        int idx = n0 + tid;
        Soff[tid] = offsets[(idx < nEnd) ? idx : nEnd];
    }
    #pragma unroll
    for (int it = 0; it < (ROWS * HID) / 512; ++it)     // 8 iters
        Af[tid + it * 512] = 0.f;

    // x (32 float4 segs/row) + u (16 segs/row): 32*48 = 1536 tasks
    #pragma unroll
    for (int it = 0; it < 3; ++it) {
        int t   = tid + it * 512;
        int row = t / 48;
        int s   = t - row * 48;
        int n   = n0 + row;
        unsigned short* Arow = &A[row * LDA_E];
        float4 v = make_float4(0.f, 0.f, 0.f, 0.f);
        int colbase;
        if (s < 32) {                                // x: cols 0..127
            if (n < N) v = ((const float4*)(x + (size_t)n * V_IN))[s];
            colbase = s * 4;
        } else {                                     // u: cols 256..319
            if (n < N) {
                int b = batch[n];
                v = ((const float4*)(u + (size_t)b * U_IN))[s - 32];
            }
            colbase = V_IN + HID + (s - 32) * 4;
        }
        uint2 o; o.x = f2bf2(v.x, v.y); o.y = f2bf2(v.z, v.w);
        *(uint2*)&Arow[colbase] = o;
    }
    __syncthreads();   // Soff + Af-zero visible

    // ---- phase 1: stage packed eidx (coalesced), row via binsearch over Soff
    const int s_base = Soff[0];
    const int total  = Soff[ROWS] - s_base;
    const int cnt    = (total < ECAP) ? total : ECAP;
    for (int i = tid; i < cnt; i += 512) {
        int j = s_base + i;
        int e = eidx[j];
        int lo = 0, hi = ROWS;                 // Soff[lo] <= j < Soff[hi]
        #pragma unroll
        for (int st = 0; st < 5; ++st) {
            int mid = (lo + hi) >> 1;
            if (Soff[mid] <= j) lo = mid; else hi = mid;
        }
        Eidx[i] = (e << 5) | lo;
    }
    __syncthreads();   // Eidx visible

    // ---- phase 2: balanced gather, task = (edge j, chunk c)
    {
        const int T = cnt * 32;
        int idx = tid;
        for (; idx + 512 < T; idx += 1024) {   // 2 tasks in flight
            int jA = idx >> 5,        cA = idx & 31;
            int jB = (idx + 512) >> 5, cB = (idx + 512) & 31;
            int pkA = Eidx[jA], pkB = Eidx[jB];
            const float* rpA = edge_attr + ((size_t)(pkA >> 5)) * HID;
            const float* rpB = edge_attr + ((size_t)(pkB >> 5)) * HID;
            int rbA = (pkA & 31) * HID, rbB = (pkB & 31) * HID;
            float vA0 = __builtin_nontemporal_load(rpA + 0  * 32 + cA);
            float vA1 = __builtin_nontemporal_load(rpA + 1  * 32 + cA);
            float vA2 = __builtin_nontemporal_load(rpA + 2  * 32 + cA);
            float vA3 = __builtin_nontemporal_load(rpA + 3  * 32 + cA);
            float vB0 = __builtin_nontemporal_load(rpB + 0  * 32 + cB);
            float vB1 = __builtin_nontemporal_load(rpB + 1  * 32 + cB);
            float vB2 = __builtin_nontemporal_load(rpB + 2  * 32 + cB);
            float vB3 = __builtin_nontemporal_load(rpB + 3  * 32 + cB);
            atomicAdd(&Af[rbA + 0 * 32 + cA], vA0);
            atomicAdd(&Af[rbA + 1 * 32 + cA], vA1);
            atomicAdd(&Af[rbA + 2 * 32 + cA], vA2);
            atomicAdd(&Af[rbA + 3 * 32 + cA], vA3);
            atomicAdd(&Af[rbB + 0 * 32 + cB], vB0);
            atomicAdd(&Af[rbB + 1 * 32 + cB], vB1);
            atomicAdd(&Af[rbB + 2 * 32 + cB], vB2);
            atomicAdd(&Af[rbB + 3 * 32 + cB], vB3);
        }
        for (; idx < T; idx += 512) {
            int j = idx >> 5, c = idx & 31;
            int pk = Eidx[j];
            const float* rp = edge_attr + ((size_t)(pk >> 5)) * HID;
            int rb = (pk & 31) * HID;
            #pragma unroll
            for (int w = 0; w < 4; ++w) {
                float v = __builtin_nontemporal_load(rp + w * 32 + c);
                atomicAdd(&Af[rb + w * 32 + c], v);
            }
        }
        // overflow fallback (cnt capped) — practically never taken
        if (total > cnt) {
            const int T2 = (total - cnt) * 32;
            for (int idx2 = tid; idx2 < T2; idx2 += 512) {
                int j = idx2 >> 5, c = idx2 & 31;
                int gj = s_base + ECAP + j;
                int e  = eidx[gj];
                int lo = 0, hi = ROWS;
                #pragma unroll
                for (int st = 0; st < 5; ++st) {
                    int mid = (lo + hi) >> 1;
                    if (Soff[mid] <= gj) lo = mid; else hi = mid;
                }
                const float* rp = edge_attr + (size_t)e * HID;
                #pragma unroll
                for (int w = 0; w < 4; ++w) {
                    float v = __builtin_nontemporal_load(rp + w * 32 + c);
                    atomicAdd(&Af[lo * HID + w * 32 + c], v);
                }
            }
        }
    }

    // ---- W fragments into registers (B-operand: col=l15, k contiguous)
    bf16x8 w1f[10], w2f[4];
    #pragma unroll
    for (int ks = 0; ks < 10; ++ks)
        w1f[ks] = *(const bf16x8*)(Wt1 + (size_t)wcol * K1 + ks * 32 + lhi * 8);
    #pragma unroll
    for (int ks = 0; ks < 4; ++ks)
        w2f[ks] = *(const bf16x8*)(Wt2 + (size_t)wcol * HID + ks * 32 + lhi * 8);
    const float b1v = b1[wcol];
    const float b2v = b2[wcol];

    __syncthreads();   // all ds_adds done

    // ---- phase 3: convert Af -> bf16 into A cols 128..255
    #pragma unroll
    for (int it = 0; it < (ROWS * HID / 2) / 512; ++it) {   // 4 iters, pairs
        int i   = tid + it * 512;          // pair index in [0, 2048)
        int row = i >> 6;
        int p   = i & 63;                  // bf16 cols 2p, 2p+1 of agg section
        float lo = Af[row * HID + p * 2];
        float hi = Af[row * HID + p * 2 + 1];
        *(unsigned int*)&A[row * LDA_E + V_IN + p * 2] = f2bf2(lo, hi);
    }
    __syncthreads();   // A complete

    // ---- layer 1: two 16-row tiles share w1f
    f32x4 acc[2] = {{0.f, 0.f, 0.f, 0.f}, {0.f, 0.f, 0.f, 0.f}};
    #pragma unroll
    for (int ks = 0; ks < 10; ++ks) {
        #pragma unroll
        for (int h = 0; h < 2; ++h) {
            bf16x8 af = *(const bf16x8*)&A[(h * 16 + l15) * LDA_E + ks * 32 + lhi * 8];
            acc[h] = __builtin_amdgcn_mfma_f32_16x16x32_bf16(af, w1f[ks], acc[h], 0, 0, 0);
        }
    }
    #pragma unroll
    for (int h = 0; h < 2; ++h)
        #pragma unroll
        for (int r = 0; r < 4; ++r) {
            float hv = fmaxf(acc[h][r] + b1v, 0.f);
            H[(h * 16 + lhi * 4 + r) * LDH_E + wcol] = f2bf(hv);
        }
    __syncthreads();

    // ---- layer 2: two 16-row tiles share w2f
    f32x4 acc2[2] = {{0.f, 0.f, 0.f, 0.f}, {0.f, 0.f, 0.f, 0.f}};
    #pragma unroll
    for (int ks = 0; ks < 4; ++ks) {
        #pragma unroll
        for (int h = 0; h < 2; ++h) {
            bf16x8 hf = *(const bf16x8*)&H[(h * 16 + l15) * LDH_E + ks * 32 + lhi * 8];
            acc2[h] = __builtin_amdgcn_mfma_f32_16x16x32_bf16(hf, w2f[ks], acc2[h], 0, 0, 0);
        }
    }
    #pragma unroll
    for (int h = 0; h < 2; ++h)
        #pragma unroll
        for (int r = 0; r < 4; ++r) {
            int n = n0 + h * 16 + lhi * 4 + r;
            if (n < N) out[(size_t)n * HID + wcol] = acc2[h][r] + b2v;
        }
}

extern "C" void kernel_launch(void* const* d_in, const int* in_sizes, int n_in,
                              void* d_out, int out_size, void* d_ws, size_t ws_size,
                              hipStream_t stream) {
    const float* x          = (const float*)d_in[0];
    const int*   edge_index = (const int*)  d_in[1];
    const float* edge_attr  = (const float*)d_in[2];
    const float* u          = (const float*)d_in[3];
    const int*   batch      = (const int*)  d_in[4];
    const float* W1         = (const float*)d_in[5];
    const float* b1         = (const float*)d_in[6];
    const float* W2         = (const float*)d_in[7];
    const float* b2         = (const float*)d_in[8];
    float* out = (float*)d_out;

    const int N = in_sizes[0] / V_IN;
    const int E = in_sizes[1] / 2;
    const int* col = edge_index + E;   // row 1 = destination

    // ws layout
    unsigned short* Wt1  = (unsigned short*)d_ws;        // 320*128 bf16
    unsigned short* Wt2  = Wt1 + (size_t)K1 * HID;       // 128*128 bf16
    int* deg       = (int*)(Wt2 + (size_t)HID * HID);
    int* cur       = deg + N;
    int* offsets   = cur + N;
    int* blockSums = offsets + N + 1;
    int* eidx      = blockSums + 2048;

    const int NB = (N + 1023) / 1024;
    const int ZP = ((N > HID * K1 ? N : HID * K1) + 255) / 256;

    zero_prep   <<<ZP, 256, 0, stream>>>(W1, W2, Wt1, Wt2, deg, N);
    hist_kernel <<<(E + 255) / 256, 256, 0, stream>>>(col, deg, E);
    scan_partial<<<NB, 256, 0, stream>>>(deg, blockSums, N);
    scan_final  <<<NB, 256, 0, stream>>>(deg, blockSums, offsets, cur, N, E);
    fill_kernel <<<(E + 255) / 256, 256, 0, stream>>>(col, cur, eidx, E);

    mlp_mfma<<<(N + ROWS - 1) / ROWS, 512, 0, stream>>>(
        x, edge_attr, offsets, eidx, u, batch, Wt1, Wt2, b1, b2, out, N);
}

// Round 13
// 200.104 us; speedup vs baseline: 2.7342x; 2.7342x over previous
//
#include <hip/hip_runtime.h>
#include <hip/hip_bf16.h>

#define V_IN 128
#define U_IN 64
#define HID 128
#define K1  (V_IN + HID + U_IN)   // 320

typedef __attribute__((ext_vector_type(8))) short bf16x8;
typedef __attribute__((ext_vector_type(4))) float f32x4;

static __device__ __forceinline__ unsigned short f2bf(float f) {
    __hip_bfloat16 h = __float2bfloat16(f);
    union { __hip_bfloat16 h; unsigned short u; } v; v.h = h;
    return v.u;
}
static __device__ __forceinline__ unsigned int f2bf2(float lo, float hi) {
    __hip_bfloat162 h2 = __float22bfloat162_rn(make_float2(lo, hi));  // v_cvt_pk_bf16_f32
    union { __hip_bfloat162 h; unsigned int u; } v; v.h = h2;
    return v.u;
}

// ---------- fused: zero deg + W1/W2 -> bf16 transposed ----------
__global__ __launch_bounds__(256) void zero_prep(
    const float* __restrict__ W1, const float* __restrict__ W2,
    unsigned short* __restrict__ Wt1, unsigned short* __restrict__ Wt2,
    int* __restrict__ deg, int N)
{
    int id = blockIdx.x * 256 + threadIdx.x;
    if (id < N) deg[id] = 0;
    if (id < HID * K1) {                     // Wt1: [128][320]
        int c = id / K1, k = id - c * K1;
        Wt1[id] = f2bf(W1[(size_t)k * HID + c]);
    }
    if (id < HID * HID) {                    // Wt2: [128][128]
        int c = id >> 7, k = id & 127;
        Wt2[id] = f2bf(W2[(size_t)k * HID + c]);
    }
}

// ---------- CSR build ----------

__global__ __launch_bounds__(256) void hist_kernel(
    const int* __restrict__ col, int* __restrict__ deg, int E)
{
    int e = blockIdx.x * 256 + threadIdx.x;
    if (e < E) atomicAdd(&deg[col[e]], 1);
}

__global__ __launch_bounds__(256) void scan_partial(
    const int* __restrict__ deg, int* __restrict__ blockSums, int N)
{
    __shared__ int sdata[256];
    int base = blockIdx.x * 1024;
    int tid  = threadIdx.x;
    int s = 0;
    #pragma unroll
    for (int j = 0; j < 4; ++j) {
        int i = base + tid * 4 + j;
        if (i < N) s += deg[i];
    }
    sdata[tid] = s;
    __syncthreads();
    for (int off = 128; off > 0; off >>= 1) {
        if (tid < off) sdata[tid] += sdata[tid + off];
        __syncthreads();
    }
    if (tid == 0) blockSums[blockIdx.x] = sdata[0];
}

// final: computes its own blockSums prefix (separate scan kernel folded in)
__global__ __launch_bounds__(256) void scan_final(
    const int* __restrict__ deg, const int* __restrict__ blockSums,
    int* __restrict__ offsets, int* __restrict__ cur, int N, int E)
{
    __shared__ int sdata[256];
    __shared__ int rdata[256];
    int tid = threadIdx.x;

    int part = 0;
    for (int i = tid; i < (int)blockIdx.x; i += 256) part += blockSums[i];
    rdata[tid] = part;
    __syncthreads();
    for (int off = 128; off > 0; off >>= 1) {
        if (tid < off) rdata[tid] += rdata[tid + off];
        __syncthreads();
    }
    const int blockPrefix = rdata[0];

    int base = blockIdx.x * 1024;
    int loc[4];
    int s = 0;
    #pragma unroll
    for (int j = 0; j < 4; ++j) {
        int i = base + tid * 4 + j;
        loc[j] = (i < N) ? deg[i] : 0;
        s += loc[j];
    }
    int mine = s;
    sdata[tid] = s;
    __syncthreads();
    for (int off = 1; off < 256; off <<= 1) {
        int t = (tid >= off) ? sdata[tid - off] : 0;
        __syncthreads();
        sdata[tid] += t;
        __syncthreads();
    }
    int prefix = blockPrefix + sdata[tid] - mine;
    #pragma unroll
    for (int j = 0; j < 4; ++j) {
        int i = base + tid * 4 + j;
        if (i < N) { offsets[i] = prefix; cur[i] = prefix; prefix += loc[j]; }
    }
    if (blockIdx.x == 0 && tid == 0) offsets[N] = E;
}

__global__ __launch_bounds__(256) void fill_kernel(
    const int* __restrict__ col, int* __restrict__ cur,
    int* __restrict__ eidx, int E)
{
    int e = blockIdx.x * 256 + threadIdx.x;
    if (e < E) {
        int p = atomicAdd(&cur[col[e]], 1);
        eidx[p] = e;
    }
}

// ---------- fused gather + 2-layer MLP via bf16 MFMA (R11 structure) ----------
// block = 512 threads = 8 waves; wave w owns output cols [16w, 16w+15];
// ROWS = 32 nodes/block, two 16-row tiles per wave share its in-reg W frags.
// R13: gather rows assigned DYNAMICALLY via an LDS ticket counter — each
// 32-lane half-wave pops a row and runs R11's ILP-4 walk on it. ~48 LDS
// atomics/block (vs R12's 26K ds_adds — that rewrite serialized at 6% BW).
#define ROWS 32
#define LDA_E 328
#define LDH_E 136
#define ECAP 1280

__global__ __launch_bounds__(512, 4) void mlp_mfma(
    const float* __restrict__ x,
    const float* __restrict__ edge_attr,
    const int*   __restrict__ offsets,
    const int*   __restrict__ eidx,
    const float* __restrict__ u,
    const int*   __restrict__ batch,
    const unsigned short* __restrict__ Wt1,
    const unsigned short* __restrict__ Wt2,
    const float* __restrict__ b1, const float* __restrict__ b2,
    float* __restrict__ out, int N)
{
    __shared__ __align__(16) unsigned short A[ROWS * LDA_E];
    __shared__ __align__(16) unsigned short H[ROWS * LDH_E];
    __shared__ int Eidx[ECAP];
    __shared__ int Soff[ROWS + 1];
    __shared__ int ticket;
    const int tid  = threadIdx.x;
    const int n0   = blockIdx.x * ROWS;
    const int lane = tid & 63;
    const int wave = tid >> 6;       // 0..7 = which 16-col slice
    const int l15  = lane & 15;
    const int lhi  = lane >> 4;      // 0..3
    const int wcol = wave * 16 + l15;

    // ---- stage offsets slice (33 ints) and this tile's eidx slice into LDS
    const int nEnd   = (n0 + ROWS < N) ? n0 + ROWS : N;
    if (tid <= ROWS) {
        int idx = n0 + tid;
        Soff[tid] = offsets[(idx < nEnd) ? idx : nEnd];
    }
    if (tid == 0) ticket = 0;
    const int s_base = offsets[n0];
    const int s_end  = offsets[nEnd];
    const int cnt    = (s_end - s_base < ECAP) ? s_end - s_base : ECAP;
    for (int i = tid; i < cnt; i += 512) Eidx[i] = eidx[s_base + i];

    // ---- stage x (32 float4 segs/row) and u (16 segs/row): 32*48 = 1536 tasks
    #pragma unroll
    for (int it = 0; it < 3; ++it) {
        int t   = tid + it * 512;
        int row = t / 48;
        int s   = t - row * 48;
        int n   = n0 + row;
        unsigned short* Arow = &A[row * LDA_E];
        float4 v = make_float4(0.f, 0.f, 0.f, 0.f);
        int colbase;
        if (s < 32) {                                // x: cols 0..127
            if (n < N) v = ((const float4*)(x + (size_t)n * V_IN))[s];
            colbase = s * 4;
        } else {                                     // u: cols 256..319
            if (n < N) {
                int b = batch[n];
                v = ((const float4*)(u + (size_t)b * U_IN))[s - 32];
            }
            colbase = V_IN + HID + (s - 32) * 4;
        }
        uint2 o; o.x = f2bf2(v.x, v.y); o.y = f2bf2(v.z, v.w);
        *(uint2*)&Arow[colbase] = o;
    }
    __syncthreads();   // Eidx, Soff, ticket visible

    // ---- gather agg into A cols 128..255: dynamic row queue, half-wave/row,
    //      ILP-4 walks, indices from LDS, NT loads on edge_attr
    {
        const int c = tid & 31;
        for (;;) {
            int r;
            if (c == 0) r = atomicAdd(&ticket, 1);
            r = __shfl(r, 0, 32);                 // broadcast within half-wave
            if (r >= ROWS) break;
            int n = n0 + r;
            f32x4 a0 = {0.f, 0.f, 0.f, 0.f};
            f32x4 a1 = {0.f, 0.f, 0.f, 0.f};
            f32x4 a2 = {0.f, 0.f, 0.f, 0.f};
            f32x4 a3 = {0.f, 0.f, 0.f, 0.f};
            if (n < N) {
                int ls = Soff[r]     - s_base;
                int le = Soff[r + 1] - s_base;
                int j = ls;
                for (; j + 3 < le; j += 4) {
                    int e0, e1, e2, e3;
                    if (j + 3 < ECAP) {
                        e0 = Eidx[j];     e1 = Eidx[j + 1];
                        e2 = Eidx[j + 2]; e3 = Eidx[j + 3];
                    } else {
                        e0 = eidx[s_base + j];     e1 = eidx[s_base + j + 1];
                        e2 = eidx[s_base + j + 2]; e3 = eidx[s_base + j + 3];
                    }
                    f32x4 v0 = __builtin_nontemporal_load((const f32x4*)(edge_attr + (size_t)e0 * HID) + c);
                    f32x4 v1 = __builtin_nontemporal_load((const f32x4*)(edge_attr + (size_t)e1 * HID) + c);
                    f32x4 v2 = __builtin_nontemporal_load((const f32x4*)(edge_attr + (size_t)e2 * HID) + c);
                    f32x4 v3 = __builtin_nontemporal_load((const f32x4*)(edge_attr + (size_t)e3 * HID) + c);
                    a0 += v0; a1 += v1; a2 += v2; a3 += v3;
                }
                for (; j < le; ++j) {
                    int e0 = (j < ECAP) ? Eidx[j] : eidx[s_base + j];
                    a0 += __builtin_nontemporal_load((const f32x4*)(edge_attr + (size_t)e0 * HID) + c);
                }
            }
            f32x4 asum = (a0 + a1) + (a2 + a3);
            uint2 o;
            o.x = f2bf2(asum[0], asum[1]);
            o.y = f2bf2(asum[2], asum[3]);
            *(uint2*)&A[r * LDA_E + V_IN + c * 4] = o;
        }
    }

    // ---- W fragments into registers (B-operand: col=l15, k contiguous)
    bf16x8 w1f[10], w2f[4];
    #pragma unroll
    for (int ks = 0; ks < 10; ++ks)
        w1f[ks] = *(const bf16x8*)(Wt1 + (size_t)wcol * K1 + ks * 32 + lhi * 8);
    #pragma unroll
    for (int ks = 0; ks < 4; ++ks)
        w2f[ks] = *(const bf16x8*)(Wt2 + (size_t)wcol * HID + ks * 32 + lhi * 8);
    const float b1v = b1[wcol];
    const float b2v = b2[wcol];

    __syncthreads();

    // ---- layer 1: two 16-row tiles share w1f
    f32x4 acc[2] = {{0.f, 0.f, 0.f, 0.f}, {0.f, 0.f, 0.f, 0.f}};
    #pragma unroll
    for (int ks = 0; ks < 10; ++ks) {
        #pragma unroll
        for (int h = 0; h < 2; ++h) {
            bf16x8 af = *(const bf16x8*)&A[(h * 16 + l15) * LDA_E + ks * 32 + lhi * 8];
            acc[h] = __builtin_amdgcn_mfma_f32_16x16x32_bf16(af, w1f[ks], acc[h], 0, 0, 0);
        }
    }
    // bias + relu -> H (D layout: row = lhi*4+r, col = l15 in wave's slice)
    #pragma unroll
    for (int h = 0; h < 2; ++h)
        #pragma unroll
        for (int r = 0; r < 4; ++r) {
            float hv = fmaxf(acc[h][r] + b1v, 0.f);
            H[(h * 16 + lhi * 4 + r) * LDH_E + wcol] = f2bf(hv);
        }
    __syncthreads();

    // ---- layer 2: two 16-row tiles share w2f
    f32x4 acc2[2] = {{0.f, 0.f, 0.f, 0.f}, {0.f, 0.f, 0.f, 0.f}};
    #pragma unroll
    for (int ks = 0; ks < 4; ++ks) {
        #pragma unroll
        for (int h = 0; h < 2; ++h) {
            bf16x8 hf = *(const bf16x8*)&H[(h * 16 + l15) * LDH_E + ks * 32 + lhi * 8];
            acc2[h] = __builtin_amdgcn_mfma_f32_16x16x32_bf16(hf, w2f[ks], acc2[h], 0, 0, 0);
        }
    }
    #pragma unroll
    for (int h = 0; h < 2; ++h)
        #pragma unroll
        for (int r = 0; r < 4; ++r) {
            int n = n0 + h * 16 + lhi * 4 + r;
            if (n < N) out[(size_t)n * HID + wcol] = acc2[h][r] + b2v;
        }
}

extern "C" void kernel_launch(void* const* d_in, const int* in_sizes, int n_in,
                              void* d_out, int out_size, void* d_ws, size_t ws_size,
                              hipStream_t stream) {
    const float* x          = (const float*)d_in[0];
    const int*   edge_index = (const int*)  d_in[1];
    const float* edge_attr  = (const float*)d_in[2];
    const float* u          = (const float*)d_in[3];
    const int*   batch      = (const int*)  d_in[4];
    const float* W1         = (const float*)d_in[5];
    const float* b1         = (const float*)d_in[6];
    const float* W2         = (const float*)d_in[7];
    const float* b2         = (const float*)d_in[8];
    float* out = (float*)d_out;

    const int N = in_sizes[0] / V_IN;
    const int E = in_sizes[1] / 2;
    const int* col = edge_index + E;   // row 1 = destination

    // ws layout
    unsigned short* Wt1  = (unsigned short*)d_ws;        // 320*128 bf16
    unsigned short* Wt2  = Wt1 + (size_t)K1 * HID;       // 128*128 bf16
    int* deg       = (int*)(Wt2 + (size_t)HID * HID);
    int* cur       = deg + N;
    int* offsets   = cur + N;
    int* blockSums = offsets + N + 1;
    int* eidx      = blockSums + 2048;

    const int NB = (N + 1023) / 1024;
    const int ZP = ((N > HID * K1 ? N : HID * K1) + 255) / 256;

    zero_prep   <<<ZP, 256, 0, stream>>>(W1, W2, Wt1, Wt2, deg, N);
    hist_kernel <<<(E + 255) / 256, 256, 0, stream>>>(col, deg, E);
    scan_partial<<<NB, 256, 0, stream>>>(deg, blockSums, N);
    scan_final  <<<NB, 256, 0, stream>>>(deg, blockSums, offsets, cur, N, E);
    fill_kernel <<<(E + 255) / 256, 256, 0, stream>>>(col, cur, eidx, E);

    mlp_mfma<<<(N + ROWS - 1) / ROWS, 512, 0, stream>>>(
        x, edge_attr, offsets, eidx, u, batch, Wt1, Wt2, b1, b2, out, N);
}